// Round 1
// baseline (1460.010 us; speedup 1.0000x reference)
//
#include <hip/hip_runtime.h>
#include <math.h>
#include <float.h>

#define M_G 100000
#define N_Q 2048
#define DIM 256
#define BQ 128
#define BM 128
#define BK 32
#define LDT (BQ + 4)     // padded LDS row: 132 floats = 528 B, 16B-aligned
#define GCHUNK 3200
#define NCHUNK 32        // ceil(100000/3200)

// one wave per gallery row: ginv[m] = 1/max(||g_m||, eps)
__global__ __launch_bounds__(256) void ginv_kernel(const float* __restrict__ g,
                                                   float* __restrict__ ginv) {
    int gid = blockIdx.x * 256 + threadIdx.x;
    int row = gid >> 6, lane = gid & 63;
    if (row >= M_G) return;
    float4 v = ((const float4*)(g + (size_t)row * DIM))[lane];
    float ss = v.x * v.x + v.y * v.y + v.z * v.z + v.w * v.w;
    #pragma unroll
    for (int o = 32; o; o >>= 1) ss += __shfl_xor(ss, o);
    if (lane == 0) ginv[row] = 1.0f / fmaxf(sqrtf(ss), 1e-12f);
}

// 128x128 tile SGEMM + fused per-chunk argmax.
// grid = (N_Q/BQ, NCHUNK); 256 threads (16x16), 8x8 per-thread accumulator.
__global__ __launch_bounds__(256, 2) void score_kernel(
    const float* __restrict__ q, const float* __restrict__ g,
    const float* __restrict__ ginv,
    float* __restrict__ pscore, int* __restrict__ pidx)
{
    __shared__ float As[BK][LDT];   // k-major query tile
    __shared__ float Bs[BK][LDT];   // k-major gallery tile
    __shared__ float red_s[BQ][17];
    __shared__ int   red_i[BQ][17];

    const int qtile = blockIdx.x;
    const int chunk = blockIdx.y;
    const int qbase = qtile * BQ;
    const int m0    = chunk * GCHUNK;
    const int mend  = min(m0 + GCHUNK, M_G);
    const int tid = threadIdx.x;
    const int tx = tid & 15, ty = tid >> 4;

    float best[8];
    int   bidx[8];
    #pragma unroll
    for (int i = 0; i < 8; ++i) { best[i] = -FLT_MAX; bidx[i] = 0x7fffffff; }

    const int ntile = (mend - m0 + BM - 1) / BM;
    for (int mt = 0; mt < ntile; ++mt) {
        const int mbase = m0 + mt * BM;
        float acc[8][8];
        #pragma unroll
        for (int i = 0; i < 8; ++i)
            #pragma unroll
            for (int j = 0; j < 8; ++j) acc[i][j] = 0.f;

        for (int kt = 0; kt < DIM; kt += BK) {
            // stage tiles: 128 rows x 32 floats each = 1024 float4; 4 per thread
            #pragma unroll
            for (int l = 0; l < 4; ++l) {
                int f = tid + l * 256;
                int rr = f >> 3, kq = f & 7;
                float4 va = *(const float4*)(q + (size_t)(qbase + rr) * DIM + kt + kq * 4);
                As[kq * 4 + 0][rr] = va.x; As[kq * 4 + 1][rr] = va.y;
                As[kq * 4 + 2][rr] = va.z; As[kq * 4 + 3][rr] = va.w;
                int mm = mbase + rr;
                float4 vb = make_float4(0.f, 0.f, 0.f, 0.f);
                if (mm < M_G)
                    vb = *(const float4*)(g + (size_t)mm * DIM + kt + kq * 4);
                Bs[kq * 4 + 0][rr] = vb.x; Bs[kq * 4 + 1][rr] = vb.y;
                Bs[kq * 4 + 2][rr] = vb.z; Bs[kq * 4 + 3][rr] = vb.w;
            }
            __syncthreads();
            #pragma unroll 4
            for (int k = 0; k < BK; ++k) {
                float4 a0 = *(const float4*)&As[k][ty * 8];
                float4 a1 = *(const float4*)&As[k][ty * 8 + 4];
                float4 b0 = *(const float4*)&Bs[k][tx * 8];
                float4 b1 = *(const float4*)&Bs[k][tx * 8 + 4];
                float a[8] = {a0.x, a0.y, a0.z, a0.w, a1.x, a1.y, a1.z, a1.w};
                float b[8] = {b0.x, b0.y, b0.z, b0.w, b1.x, b1.y, b1.z, b1.w};
                #pragma unroll
                for (int i = 0; i < 8; ++i)
                    #pragma unroll
                    for (int j = 0; j < 8; ++j)
                        acc[i][j] = fmaf(a[i], b[j], acc[i][j]);
            }
            __syncthreads();
        }
        // fused scoring: scale by ginv[m], track per-thread best (first-max tie-break)
        #pragma unroll
        for (int j = 0; j < 8; ++j) {
            int m = mbase + tx * 8 + j;
            if (m < mend) {
                float gi = ginv[m];
                #pragma unroll
                for (int i = 0; i < 8; ++i) {
                    float s = acc[i][j] * gi;
                    if (s > best[i]) { best[i] = s; bidx[i] = m; }
                }
            }
        }
    }

    // block reduction: 16 threads (tx) per query row
    #pragma unroll
    for (int i = 0; i < 8; ++i) {
        red_s[ty * 8 + i][tx] = best[i];
        red_i[ty * 8 + i][tx] = bidx[i];
    }
    __syncthreads();
    if (tid < BQ) {
        float bs = -FLT_MAX; int bi = 0x7fffffff;
        #pragma unroll
        for (int t = 0; t < 16; ++t) {
            float s = red_s[tid][t]; int ix = red_i[tid][t];
            if (s > bs || (s == bs && ix < bi)) { bs = s; bi = ix; }
        }
        pscore[(size_t)(qbase + tid) * NCHUNK + chunk] = bs;
        pidx[(size_t)(qbase + tid) * NCHUNK + chunk]  = bi;
    }
}

// reduce 32 chunk-partials per query, then gather the int outputs
__global__ __launch_bounds__(256) void final_kernel(
    const float* __restrict__ pscore, const int* __restrict__ pidx,
    const int* __restrict__ cat, const int* __restrict__ shp,
    int* __restrict__ out)
{
    int qidx = blockIdx.x * 256 + threadIdx.x;
    if (qidx >= N_Q) return;
    float bs = -FLT_MAX; int bi = 0x7fffffff;
    #pragma unroll
    for (int c = 0; c < NCHUNK; ++c) {
        float s = pscore[(size_t)qidx * NCHUNK + c];
        int ix = pidx[(size_t)qidx * NCHUNK + c];
        if (s > bs || (s == bs && ix < bi)) { bs = s; bi = ix; }
    }
    out[qidx] = cat[bi];
    out[N_Q + qidx] = shp[bi];
}

extern "C" void kernel_launch(void* const* d_in, const int* in_sizes, int n_in,
                              void* d_out, int out_size, void* d_ws, size_t ws_size,
                              hipStream_t stream) {
    const float* q  = (const float*)d_in[0];   // [2048,256] fp32
    const float* g  = (const float*)d_in[1];   // [100000,256] fp32
    const int* cat  = (const int*)d_in[2];     // [100000] int32
    const int* shp  = (const int*)d_in[3];     // [100000] int32
    int* out = (int*)d_out;                    // [2048 cat | 2048 shape] int32

    float* ginv   = (float*)d_ws;                            // 100000 f32
    float* pscore = ginv + M_G;                              // 2048*32 f32
    int*   pidx   = (int*)(pscore + (size_t)N_Q * NCHUNK);   // 2048*32 i32

    ginv_kernel<<<(M_G + 3) / 4, 256, 0, stream>>>(g, ginv);
    dim3 grid(N_Q / BQ, NCHUNK);
    score_kernel<<<grid, 256, 0, stream>>>(q, g, ginv, pscore, pidx);
    final_kernel<<<(N_Q + 255) / 256, 256, 0, stream>>>(pscore, pidx, cat, shp, out);
}

// Round 2
// 467.541 us; speedup vs baseline: 3.1227x; 3.1227x over previous
//
#include <hip/hip_runtime.h>
#include <math.h>
#include <float.h>

#define M_G 100000
#define N_Q 2048
#define DIM 256
#define BQ 128
#define BM 128
#define BK 32
#define NGROUP 1563          // ceil(M_G/64)
#define NMT 782              // ceil(M_G/128)
#define MARGIN 0.017f        // 2*(2^-8 + 2^-8 + accum) + slack, normalized-score space

typedef __bf16 bf16x8 __attribute__((ext_vector_type(8)));
typedef float f32x4 __attribute__((ext_vector_type(4)));

// round-half-up fp32->bf16, packed pair (a -> low ushort, b -> high ushort)
__device__ inline unsigned pack_bf16_rhu(float a, float b) {
    unsigned ua = __float_as_uint(a) + 0x8000u;
    unsigned ub = __float_as_uint(b) + 0x8000u;
    return (ua >> 16) | (ub & 0xFFFF0000u);
}

// ginv[m] = 1/max(||g_m||, eps); one wave per gallery row
__global__ __launch_bounds__(256) void ginv_kernel(const float* __restrict__ g,
                                                   float* __restrict__ ginv) {
    int gid = blockIdx.x * 256 + threadIdx.x;
    int row = gid >> 6, lane = gid & 63;
    if (row >= M_G) return;
    float4 v = ((const float4*)(g + (size_t)row * DIM))[lane];
    float ss = v.x * v.x + v.y * v.y + v.z * v.z + v.w * v.w;
    #pragma unroll
    for (int o = 32; o; o >>= 1) ss += __shfl_xor(ss, o);
    if (lane == 0) ginv[row] = 1.0f / fmaxf(sqrtf(ss), 1e-12f);
}

// normalize q rows (argmax-invariant positive scale) and convert to bf16
__global__ __launch_bounds__(256) void qprep_kernel(const float* __restrict__ q,
                                                    unsigned short* __restrict__ qbf) {
    int wid = threadIdx.x >> 6, lane = threadIdx.x & 63;
    int row = blockIdx.x * 4 + wid;
    if (row >= N_Q) return;
    float4 v = ((const float4*)(q + (size_t)row * DIM))[lane];
    float ss = v.x * v.x + v.y * v.y + v.z * v.z + v.w * v.w;
    #pragma unroll
    for (int o = 32; o; o >>= 1) ss += __shfl_xor(ss, o);
    float inv = 1.0f / fmaxf(sqrtf(ss), 1e-12f);
    unsigned w0 = pack_bf16_rhu(v.x * inv, v.y * inv);
    unsigned w1 = pack_bf16_rhu(v.z * inv, v.w * inv);
    ((uint2*)(qbf + (size_t)row * DIM))[lane] = make_uint2(w0, w1);
}

// Phase A: bf16 MFMA GEMM (gallery rows = A/M-dim, queries = B/N-dim).
// Writes per-(64-row-group, query) max of ginv-scaled scores into bmax.
__global__ __launch_bounds__(256) void scoreA_kernel(
    const unsigned short* __restrict__ qbf, const float* __restrict__ g,
    const float* __restrict__ ginv, float* __restrict__ bmax)
{
    __shared__ __align__(16) unsigned short Gs[BM * BK];
    __shared__ __align__(16) unsigned short Qs[BQ * BK];
    __shared__ float ginv_s[BM];

    const int qt = blockIdx.x, mt = blockIdx.y;
    const int qb = qt * BQ, mb = mt * BM;
    const int tid = threadIdx.x;
    const int wid = tid >> 6, lane = tid & 63;
    const int wm = wid & 1, wq = wid >> 1;
    const int r16 = lane & 15;
    const int k8 = (lane >> 4) * 8;

    if (tid < BM) {
        int m = mb + tid;
        ginv_s[tid] = (m < M_G) ? ginv[m] : 0.0f;
    }

    f32x4 acc[4][4];
    #pragma unroll
    for (int fi = 0; fi < 4; ++fi)
        #pragma unroll
        for (int fj = 0; fj < 4; ++fj)
            acc[fi][fj] = (f32x4){0.f, 0.f, 0.f, 0.f};

    for (int kt = 0; kt < DIM; kt += BK) {
        // stage gallery tile: fp32 load -> bf16 round-half-up -> LDS [row][k]
        #pragma unroll
        for (int l = 0; l < 4; ++l) {
            int c = l * 256 + tid;           // 1024 chunks of 4 elems
            int row = c >> 3, kq = c & 7;
            int m = mb + row;
            float4 v = make_float4(0.f, 0.f, 0.f, 0.f);
            if (m < M_G) v = *(const float4*)(g + (size_t)m * DIM + kt + kq * 4);
            uint2 w;
            w.x = pack_bf16_rhu(v.x, v.y);
            w.y = pack_bf16_rhu(v.z, v.w);
            *(uint2*)(Gs + row * BK + kq * 4) = w;
        }
        // stage query tile: bf16 copy (16B chunks)
        #pragma unroll
        for (int l = 0; l < 2; ++l) {
            int c = l * 256 + tid;           // 512 chunks of 8 elems
            int row = c >> 2, kq = c & 3;
            uint4 v = *(const uint4*)(qbf + (size_t)(qb + row) * DIM + kt + kq * 8);
            *(uint4*)(Qs + row * BK + kq * 8) = v;
        }
        __syncthreads();

        bf16x8 af[4], bfr[4];
        #pragma unroll
        for (int fi = 0; fi < 4; ++fi)
            af[fi] = *(bf16x8*)(Gs + (wm * 64 + fi * 16 + r16) * BK + k8);
        #pragma unroll
        for (int fj = 0; fj < 4; ++fj)
            bfr[fj] = *(bf16x8*)(Qs + (wq * 64 + fj * 16 + r16) * BK + k8);
        #pragma unroll
        for (int fi = 0; fi < 4; ++fi)
            #pragma unroll
            for (int fj = 0; fj < 4; ++fj)
                acc[fi][fj] = __builtin_amdgcn_mfma_f32_16x16x32_bf16(
                    af[fi], bfr[fj], acc[fi][fj], 0, 0, 0);
        __syncthreads();
    }

    // epilogue: scale by ginv, mask OOB rows, per-query-column max over 64 rows
    const int rhi = lane >> 4;
    float colmax[4] = {-FLT_MAX, -FLT_MAX, -FLT_MAX, -FLT_MAX};
    #pragma unroll
    for (int fi = 0; fi < 4; ++fi) {
        #pragma unroll
        for (int j = 0; j < 4; ++j) {
            int ml = wm * 64 + fi * 16 + rhi * 4 + j;
            float gi = ginv_s[ml];
            bool valid = (mb + ml) < M_G;
            #pragma unroll
            for (int fj = 0; fj < 4; ++fj) {
                float s = acc[fi][fj][j] * gi;
                colmax[fj] = fmaxf(colmax[fj], valid ? s : -FLT_MAX);
            }
        }
    }
    int group = mt * 2 + wm;
    #pragma unroll
    for (int fj = 0; fj < 4; ++fj) {
        float v = colmax[fj];
        v = fmaxf(v, __shfl_xor(v, 16));
        v = fmaxf(v, __shfl_xor(v, 32));
        if (lane < 16 && group < NGROUP)
            bmax[(size_t)group * N_Q + qb + wq * 64 + fj * 16 + lane] = v;
    }
}

// per-query global max of bmax -> s1
__global__ __launch_bounds__(256) void s1red_kernel(const float* __restrict__ bmax,
                                                    float* __restrict__ s1) {
    int wid = threadIdx.x >> 6, lane = threadIdx.x & 63;
    int q = blockIdx.x * 4 + wid;
    if (q >= N_Q) return;
    float bs = -FLT_MAX;
    for (int gr = lane; gr < NGROUP; gr += 64)
        bs = fmaxf(bs, bmax[(size_t)gr * N_Q + q]);
    #pragma unroll
    for (int o = 32; o; o >>= 1) bs = fmaxf(bs, __shfl_xor(bs, o));
    if (lane == 0) s1[q] = bs;
}

// Phase B: exact fp32 rescore of all groups within MARGIN of the bf16 top-1
__global__ __launch_bounds__(256) void phaseB_kernel(
    const float* __restrict__ q, const float* __restrict__ g,
    const float* __restrict__ ginv, const float* __restrict__ bmax,
    const float* __restrict__ s1,
    const int* __restrict__ cat, const int* __restrict__ shp,
    int* __restrict__ out)
{
    __shared__ __align__(16) float qrow[DIM];
    __shared__ int glist[NGROUP];
    __shared__ int ng;
    __shared__ float rbs[4];
    __shared__ int rbi[4];

    const int qi = blockIdx.x;
    const int tid = threadIdx.x;
    if (tid < 64)
        *(float4*)&qrow[tid * 4] = *(const float4*)(q + (size_t)qi * DIM + tid * 4);
    if (tid == 0) ng = 0;
    __syncthreads();

    const float thr = s1[qi] - MARGIN;
    for (int gr = tid; gr < NGROUP; gr += 256)
        if (bmax[(size_t)gr * N_Q + qi] >= thr)
            glist[atomicAdd(&ng, 1)] = gr;
    __syncthreads();

    float bs = -FLT_MAX;
    int bi = 0x7fffffff;
    const int r = tid >> 2, p = tid & 3;
    const int n = ng;
    for (int i = 0; i < n; ++i) {
        int m = glist[i] * 64 + r;
        if (m < M_G) {
            const float* grow = g + (size_t)m * DIM + p * 64;
            const float* qr = qrow + p * 64;
            float s = 0.f;
            #pragma unroll
            for (int j = 0; j < 16; ++j) {
                float4 gv = *(const float4*)(grow + j * 4);
                float4 qv = *(const float4*)(qr + j * 4);
                s += gv.x * qv.x + gv.y * qv.y + gv.z * qv.z + gv.w * qv.w;
            }
            s += __shfl_xor(s, 1);
            s += __shfl_xor(s, 2);
            s *= ginv[m];
            if (p == 0 && (s > bs || (s == bs && m < bi))) { bs = s; bi = m; }
        }
    }
    #pragma unroll
    for (int o = 1; o < 64; o <<= 1) {
        float os = __shfl_xor(bs, o);
        int oi = __shfl_xor(bi, o);
        if (os > bs || (os == bs && oi < bi)) { bs = os; bi = oi; }
    }
    const int lane = tid & 63, wid = tid >> 6;
    if (lane == 0) { rbs[wid] = bs; rbi[wid] = bi; }
    __syncthreads();
    if (tid == 0) {
        #pragma unroll
        for (int w = 1; w < 4; ++w)
            if (rbs[w] > bs || (rbs[w] == bs && rbi[w] < bi)) { bs = rbs[w]; bi = rbi[w]; }
        out[qi] = cat[bi];
        out[N_Q + qi] = shp[bi];
    }
}

extern "C" void kernel_launch(void* const* d_in, const int* in_sizes, int n_in,
                              void* d_out, int out_size, void* d_ws, size_t ws_size,
                              hipStream_t stream) {
    const float* q = (const float*)d_in[0];    // [2048,256] fp32
    const float* g = (const float*)d_in[1];    // [100000,256] fp32
    const int* cat = (const int*)d_in[2];      // [100000] int32
    const int* shp = (const int*)d_in[3];      // [100000] int32
    int* out = (int*)d_out;                    // [2048 cat | 2048 shape] int32

    char* ws = (char*)d_ws;
    unsigned short* qbf = (unsigned short*)(ws);                 // 1,048,576 B
    float* ginv = (float*)(ws + 1048576);                        // 400,000 B
    float* s1   = (float*)(ws + 1048576 + 400128);               // 8,192 B
    float* bmax = (float*)(ws + 1048576 + 400128 + 8192);        // 12,804,096 B
    // total ws need ~14.26 MB

    ginv_kernel<<<(M_G + 3) / 4, 256, 0, stream>>>(g, ginv);
    qprep_kernel<<<N_Q / 4, 256, 0, stream>>>(q, qbf);
    dim3 gridA(N_Q / BQ, NMT);   // x = qtile (fastest) so 16 blocks share one m-tile in L2
    scoreA_kernel<<<gridA, 256, 0, stream>>>(qbf, g, ginv, bmax);
    s1red_kernel<<<N_Q / 4, 256, 0, stream>>>(bmax, s1);
    phaseB_kernel<<<N_Q, 256, 0, stream>>>(q, g, ginv, bmax, s1, cat, shp, out);
}

// Round 3
// 240.949 us; speedup vs baseline: 6.0594x; 1.9404x over previous
//
#include <hip/hip_runtime.h>
#include <math.h>
#include <float.h>

#define M_G 100000
#define N_Q 2048
#define DIM 256
#define NMT 782              // ceil(M_G/128) m-tiles
#define NG2 1564             // groups of 64 rows = NMT*2
#define GSTRIDE 1568         // padded group stride for bmaxT rows
#define MARGIN 0.012f        // > 2*(2^-8) bf16 dot error bound, 1.5x slack

typedef __bf16 bf16x8 __attribute__((ext_vector_type(8)));
typedef float f32x4 __attribute__((ext_vector_type(4)));

// ws layout (bytes)
#define WS_GP    0                   // 782 * 65536 = 51,249,152  packed gallery
#define WS_QP    51249152            // 16 * 65536  =  1,048,576  packed queries
#define WS_BMAX  52297728            // 2048*1568*4 = 12,845,056  per-(q,group) bf16 max
#define WS_S1U   65142784            // 2048*4                    per-q max (encoded uint)

__device__ inline unsigned pack_bf16_rhu(float a, float b) {
    unsigned ua = __float_as_uint(a) + 0x8000u;
    unsigned ub = __float_as_uint(b) + 0x8000u;
    return (ua >> 16) | (ub & 0xFFFF0000u);
}
__device__ inline unsigned enc_f32(float s) {   // order-preserving float->uint
    unsigned b = __float_as_uint(s);
    return b ^ (((unsigned)((int)b >> 31)) | 0x80000000u);
}
__device__ inline float dec_f32(unsigned u) {
    unsigned b = (u & 0x80000000u) ? (u ^ 0x80000000u) : ~u;
    return __uint_as_float(b);
}
__device__ inline void gload_lds16(const void* gsrc, void* ldst) {
    __builtin_amdgcn_global_load_lds(
        (const __attribute__((address_space(1))) unsigned int*)gsrc,
        (__attribute__((address_space(3))) unsigned int*)ldst, 16, 0, 0);
}

__global__ __launch_bounds__(256) void init_kernel(unsigned* __restrict__ s1u) {
    int i = blockIdx.x * 256 + threadIdx.x;
    if (i < N_Q) s1u[i] = 0u;
}

// Normalize rows, convert to bf16 (round-half-up), store in per-tile swizzled
// LDS image layout: tile mt (128 rows x 256 k) = 4 k-steps x 16KB; within a
// k-step, 16B granule (row, gg) lives at uint4 index row*8 + (gg ^ (row&7)).
__global__ __launch_bounds__(256) void gpack_kernel(const float* __restrict__ g,
                                                    uint4* __restrict__ gp) {
    int row = blockIdx.x * 4 + (threadIdx.x >> 6);
    int lane = threadIdx.x & 63;
    if (row >= M_G) return;
    const float4* grow = (const float4*)(g + (size_t)row * DIM);
    float4 v = grow[lane];
    float ss = v.x * v.x + v.y * v.y + v.z * v.z + v.w * v.w;
    #pragma unroll
    for (int o = 32; o; o >>= 1) ss += __shfl_xor(ss, o);
    float gi = 1.0f / fmaxf(sqrtf(ss), 1e-12f);
    if (lane < 32) {
        float4 a = grow[lane * 2], b = grow[lane * 2 + 1];
        uint4 w;
        w.x = pack_bf16_rhu(a.x * gi, a.y * gi);
        w.y = pack_bf16_rhu(a.z * gi, a.w * gi);
        w.z = pack_bf16_rhu(b.x * gi, b.y * gi);
        w.w = pack_bf16_rhu(b.z * gi, b.w * gi);
        int mt = row >> 7, rl = row & 127, ks = lane >> 3, gg = lane & 7;
        gp[(size_t)mt * 4096 + ks * 1024 + rl * 8 + (gg ^ (rl & 7))] = w;
    }
}

__global__ __launch_bounds__(256) void qpack_kernel(const float* __restrict__ q,
                                                    uint4* __restrict__ qp) {
    int row = blockIdx.x * 4 + (threadIdx.x >> 6);
    int lane = threadIdx.x & 63;
    if (row >= N_Q) return;
    const float4* qrow = (const float4*)(q + (size_t)row * DIM);
    float4 v = qrow[lane];
    float ss = v.x * v.x + v.y * v.y + v.z * v.z + v.w * v.w;
    #pragma unroll
    for (int o = 32; o; o >>= 1) ss += __shfl_xor(ss, o);
    float qi = 1.0f / fmaxf(sqrtf(ss), 1e-12f);
    if (lane < 32) {
        float4 a = qrow[lane * 2], b = qrow[lane * 2 + 1];
        uint4 w;
        w.x = pack_bf16_rhu(a.x * qi, a.y * qi);
        w.y = pack_bf16_rhu(a.z * qi, a.w * qi);
        w.z = pack_bf16_rhu(b.x * qi, b.y * qi);
        w.w = pack_bf16_rhu(b.z * qi, b.w * qi);
        int qt = row >> 7, rl = row & 127, ks = lane >> 3, gg = lane & 7;
        qp[(size_t)qt * 4096 + ks * 1024 + rl * 8 + (gg ^ (rl & 7))] = w;
    }
}

// Phase A: bf16 MFMA GEMM on pre-packed tiles. 128x128 tile, BK=64, 4 waves,
// global_load_lds staging, swizzled conflict-free ds_read_b128 fragments.
// Per (q, 64-row group): bmaxT[q][group] = max score; s1u[q] = atomicMax.
__global__ __launch_bounds__(256) void scoreA_kernel(
    const uint4* __restrict__ gp, const uint4* __restrict__ qp,
    float* __restrict__ bmaxT, unsigned* __restrict__ s1u)
{
    __shared__ __align__(16) char lds[32768];   // Gs [0,16K) | Qs [16K,32K)

    // XCD-chunked mapping: xcd owns contiguous m-tile range, q-tile fastest
    const int bid = blockIdx.x;
    const int xcd = bid & 7, j = bid >> 3;
    const int csz = (xcd < 6) ? 98 : 97;
    const int cbase = (xcd < 6) ? xcd * 98 : 588 + (xcd - 6) * 97;
    if (j >= csz * 16) return;
    const int qt = j & 15;
    const int mt = cbase + (j >> 4);

    const int tid = threadIdx.x;
    const int wid = tid >> 6, lane = tid & 63;
    const int wm = wid & 1, wq = wid >> 1;
    const int r16 = lane & 15, rhi = lane >> 4;

    f32x4 acc[4][4];
    #pragma unroll
    for (int fi = 0; fi < 4; ++fi)
        #pragma unroll
        for (int fj = 0; fj < 4; ++fj)
            acc[fi][fj] = (f32x4){0.f, 0.f, 0.f, 0.f};

    const uint4* gsrc = gp + (size_t)mt * 4096;
    const uint4* qsrc = qp + (size_t)qt * 4096;

    for (int kt = 0; kt < 4; ++kt) {
        // stage 16KB + 16KB: 8 x 1KB wave-issues per wave, linear copy
        #pragma unroll
        for (int l = 0; l < 4; ++l) {
            int c = wid * 4 + l;
            gload_lds16(gsrc + kt * 1024 + c * 64 + lane, lds + c * 1024);
            gload_lds16(qsrc + kt * 1024 + c * 64 + lane, lds + 16384 + c * 1024);
        }
        __syncthreads();
        #pragma unroll
        for (int kk = 0; kk < 2; ++kk) {
            const int gb = kk * 4 + rhi;   // k-granule 0..7
            bf16x8 af[4], bfr[4];
            #pragma unroll
            for (int fi = 0; fi < 4; ++fi) {
                int row = wm * 64 + fi * 16 + r16;
                af[fi] = *(const bf16x8*)(lds + row * 128 + ((gb ^ (row & 7)) << 4));
            }
            #pragma unroll
            for (int fj = 0; fj < 4; ++fj) {
                int row = wq * 64 + fj * 16 + r16;
                bfr[fj] = *(const bf16x8*)(lds + 16384 + row * 128 + ((gb ^ (row & 7)) << 4));
            }
            #pragma unroll
            for (int fi = 0; fi < 4; ++fi)
                #pragma unroll
                for (int fj = 0; fj < 4; ++fj)
                    acc[fi][fj] = __builtin_amdgcn_mfma_f32_16x16x32_bf16(
                        af[fi], bfr[fj], acc[fi][fj], 0, 0, 0);
        }
        __syncthreads();
    }

    // epilogue: per-query max over this wave's 64 gallery rows (one group)
    float colmax[4] = {-FLT_MAX, -FLT_MAX, -FLT_MAX, -FLT_MAX};
    #pragma unroll
    for (int fi = 0; fi < 4; ++fi) {
        #pragma unroll
        for (int jj = 0; jj < 4; ++jj) {
            int ml = wm * 64 + fi * 16 + rhi * 4 + jj;
            bool valid = (mt * 128 + ml) < M_G;
            #pragma unroll
            for (int fj = 0; fj < 4; ++fj) {
                float s = acc[fi][fj][jj];
                colmax[fj] = fmaxf(colmax[fj], valid ? s : -FLT_MAX);
            }
        }
    }
    const int group = mt * 2 + wm;
    #pragma unroll
    for (int fj = 0; fj < 4; ++fj) {
        float v = colmax[fj];
        v = fmaxf(v, __shfl_xor(v, 16));
        v = fmaxf(v, __shfl_xor(v, 32));
        if (lane < 16) {
            int qn = qt * 128 + wq * 64 + fj * 16 + lane;
            bmaxT[(size_t)qn * GSTRIDE + group] = v;
            atomicMax(&s1u[qn], enc_f32(v));
        }
    }
}

// Phase B: exact fp32 rescore of candidate groups (within MARGIN of bf16 top-1).
// Row norm recomputed in-register; tie-break = lowest index (np.argmax).
__global__ __launch_bounds__(256) void phaseB_kernel(
    const float* __restrict__ q, const float* __restrict__ g,
    const float* __restrict__ bmaxT, const unsigned* __restrict__ s1u,
    const int* __restrict__ cat, const int* __restrict__ shp,
    int* __restrict__ out)
{
    __shared__ __align__(16) float qrow[DIM];
    __shared__ int glist[NG2];
    __shared__ int ng;
    __shared__ float rbs[4];
    __shared__ int rbi[4];

    const int qi = blockIdx.x;
    const int tid = threadIdx.x;
    if (tid < 64)
        *(float4*)&qrow[tid * 4] = *(const float4*)(q + (size_t)qi * DIM + tid * 4);
    if (tid == 0) ng = 0;
    __syncthreads();

    const float thr = dec_f32(s1u[qi]) - MARGIN;
    for (int gr = tid; gr < NG2; gr += 256)
        if (bmaxT[(size_t)qi * GSTRIDE + gr] >= thr)
            glist[atomicAdd(&ng, 1)] = gr;
    __syncthreads();

    float bs = -FLT_MAX;
    int bi = 0x7fffffff;
    const int r = tid >> 2, p = tid & 3;
    const int n = ng;
    for (int i = 0; i < n; ++i) {
        int m = glist[i] * 64 + r;
        if (m < M_G) {
            const float* grow = g + (size_t)m * DIM + p * 64;
            const float* qr = qrow + p * 64;
            float s = 0.f, ssq = 0.f;
            #pragma unroll
            for (int jj = 0; jj < 16; ++jj) {
                float4 gv = *(const float4*)(grow + jj * 4);
                float4 qv = *(const float4*)(qr + jj * 4);
                s += gv.x * qv.x + gv.y * qv.y + gv.z * qv.z + gv.w * qv.w;
                ssq += gv.x * gv.x + gv.y * gv.y + gv.z * gv.z + gv.w * gv.w;
            }
            s += __shfl_xor(s, 1);  s += __shfl_xor(s, 2);
            ssq += __shfl_xor(ssq, 1);  ssq += __shfl_xor(ssq, 2);
            s *= 1.0f / fmaxf(sqrtf(ssq), 1e-12f);
            if (p == 0 && (s > bs || (s == bs && m < bi))) { bs = s; bi = m; }
        }
    }
    #pragma unroll
    for (int o = 1; o < 64; o <<= 1) {
        float os = __shfl_xor(bs, o);
        int oi = __shfl_xor(bi, o);
        if (os > bs || (os == bs && oi < bi)) { bs = os; bi = oi; }
    }
    const int lane = tid & 63, wid = tid >> 6;
    if (lane == 0) { rbs[wid] = bs; rbi[wid] = bi; }
    __syncthreads();
    if (tid == 0) {
        #pragma unroll
        for (int w = 1; w < 4; ++w)
            if (rbs[w] > bs || (rbs[w] == bs && rbi[w] < bi)) { bs = rbs[w]; bi = rbi[w]; }
        out[qi] = cat[bi];
        out[N_Q + qi] = shp[bi];
    }
}

extern "C" void kernel_launch(void* const* d_in, const int* in_sizes, int n_in,
                              void* d_out, int out_size, void* d_ws, size_t ws_size,
                              hipStream_t stream) {
    const float* q = (const float*)d_in[0];    // [2048,256] fp32
    const float* g = (const float*)d_in[1];    // [100000,256] fp32
    const int* cat = (const int*)d_in[2];      // [100000] int32
    const int* shp = (const int*)d_in[3];      // [100000] int32
    int* out = (int*)d_out;                    // [2048 cat | 2048 shape] int32

    char* ws = (char*)d_ws;
    uint4* gp        = (uint4*)(ws + WS_GP);
    uint4* qp        = (uint4*)(ws + WS_QP);
    float* bmaxT     = (float*)(ws + WS_BMAX);
    unsigned* s1u    = (unsigned*)(ws + WS_S1U);

    init_kernel<<<8, 256, 0, stream>>>(s1u);
    gpack_kernel<<<M_G / 4, 256, 0, stream>>>(g, gp);
    qpack_kernel<<<N_Q / 4, 256, 0, stream>>>(q, qp);
    scoreA_kernel<<<12544, 256, 0, stream>>>(gp, qp, bmaxT, s1u);
    phaseB_kernel<<<N_Q, 256, 0, stream>>>(q, g, bmaxT, s1u, cat, shp, out);
}

// Round 4
// 234.603 us; speedup vs baseline: 6.2233x; 1.0271x over previous
//
#include <hip/hip_runtime.h>
#include <math.h>
#include <float.h>

#define M_G 100000
#define N_Q 2048
#define DIM 256
#define NMT 391              // 256-row gallery tiles
#define NG2 1564             // 64-row groups = NMT*4
#define GSTRIDE 1568         // padded group stride for bmaxT rows
#define MARGIN 0.012f        // > 2*(2^-8) bf16 dot error bound, 1.5x slack

typedef __bf16 bf16x8 __attribute__((ext_vector_type(8)));
typedef float f32x4 __attribute__((ext_vector_type(4)));

// ws layout (bytes)
#define WS_GP    0                   // 391 tiles * 128KB = 51,249,152
#define WS_QP    51249152            // 8 tiles * 128KB   =  1,048,576
#define WS_BMAX  52297728            // 2048*1568*4       = 12,845,056

__device__ inline unsigned pack_bf16_rhu(float a, float b) {
    unsigned ua = __float_as_uint(a) + 0x8000u;
    unsigned ub = __float_as_uint(b) + 0x8000u;
    return (ua >> 16) | (ub & 0xFFFF0000u);
}
__device__ inline void gload_lds16(const void* gsrc, void* ldst) {
    __builtin_amdgcn_global_load_lds(
        (const __attribute__((address_space(1))) unsigned int*)gsrc,
        (__attribute__((address_space(3))) unsigned int*)ldst, 16, 0, 0);
}

// Normalize rows, fp32->bf16 (round-half-up), store in the tile/K-step/half
// pre-swizzled LDS image layout. Tile = 256 rows; K-step = 64 k; half = 128 rows.
// Chunk c = (tile*4 + kt)*2 + half (16KB = 1024 uint4); granule (rl, gg) at
// uint4 index rl*8 + (gg ^ (rl&7)).  Blocks < 25000: gallery; else queries.
__global__ __launch_bounds__(256) void pack_kernel(
    const float* __restrict__ g, const float* __restrict__ q,
    uint4* __restrict__ gp, uint4* __restrict__ qp)
{
    const int b = blockIdx.x;
    const int wid4 = threadIdx.x >> 6, lane = threadIdx.x & 63;
    const float* src;
    uint4* dst;
    int row;
    if (b < 25000) { row = b * 4 + wid4; src = g + (size_t)row * DIM; dst = gp; }
    else           { row = (b - 25000) * 4 + wid4; src = q + (size_t)row * DIM; dst = qp; }
    float4 v = ((const float4*)src)[lane];
    float ss = v.x * v.x + v.y * v.y + v.z * v.z + v.w * v.w;
    #pragma unroll
    for (int o = 32; o; o >>= 1) ss += __shfl_xor(ss, o);
    float inv = 1.0f / fmaxf(sqrtf(ss), 1e-12f);
    if (lane < 32) {
        float4 a = ((const float4*)src)[lane * 2];
        float4 c = ((const float4*)src)[lane * 2 + 1];
        uint4 w;
        w.x = pack_bf16_rhu(a.x * inv, a.y * inv);
        w.y = pack_bf16_rhu(a.z * inv, a.w * inv);
        w.z = pack_bf16_rhu(c.x * inv, c.y * inv);
        w.w = pack_bf16_rhu(c.z * inv, c.w * inv);
        int mt = row >> 8, half = (row >> 7) & 1, rl = row & 127;
        int kt = lane >> 3, gg = lane & 7;
        dst[(size_t)((mt * 4 + kt) * 2 + half) * 1024 + rl * 8 + (gg ^ (rl & 7))] = w;
    }
}

#define BAR __builtin_amdgcn_s_barrier()
#define LGKM0 { asm volatile("s_waitcnt lgkmcnt(0)" ::: "memory"); \
                __builtin_amdgcn_sched_barrier(0); }
#define VMCNT(n) { asm volatile("s_waitcnt vmcnt(" #n ")" ::: "memory"); \
                   __builtin_amdgcn_sched_barrier(0); }

#define READ_A(bufb, mi) { _Pragma("unroll") \
  for (int f_ = 0; f_ < 4; ++f_) { \
    const char* p_ = lds + (bufb) + (wr * 64 + f_ * 16 + (mi) * 128 + r16) * 128; \
    aR[f_ * 2]     = *(const bf16x8*)(p_ + sw0); \
    aR[f_ * 2 + 1] = *(const bf16x8*)(p_ + sw1); } }

#define READ_B(bufb, ni) { _Pragma("unroll") \
  for (int f_ = 0; f_ < 2; ++f_) { \
    const char* p_ = lds + (bufb) + 32768 + (wc * 32 + f_ * 16 + (ni) * 128 + r16) * 128; \
    bR[f_ * 2]     = *(const bf16x8*)(p_ + sw0); \
    bR[f_ * 2 + 1] = *(const bf16x8*)(p_ + sw1); } }

#define MFMA16(mi, ni) { _Pragma("unroll") \
  for (int f_ = 0; f_ < 4; ++f_) { _Pragma("unroll") \
    for (int j_ = 0; j_ < 2; ++j_) { _Pragma("unroll") \
      for (int k_ = 0; k_ < 2; ++k_) \
        acc[(mi) * 4 + f_][(ni) * 2 + j_] = __builtin_amdgcn_mfma_f32_16x16x32_bf16( \
            aR[f_ * 2 + k_], bR[j_ * 2 + k_], acc[(mi) * 4 + f_][(ni) * 2 + j_], 0, 0, 0); } } }

#define STAGE_HALF(dstoff, srcptr) { \
  const uint4* s_ = (srcptr); \
  gload_lds16(s_ + tid,       lds + (dstoff) + tid * 16); \
  gload_lds16(s_ + tid + 512, lds + (dstoff) + 8192 + tid * 16); }

#define GA(kt, h) (gsrc + (size_t)((kt) * 2 + (h)) * 1024)
#define QB(kt, h) (qsrc + (size_t)((kt) * 2 + (h)) * 1024)

// Phase A: 256x256 bf16 MFMA tile, 8 waves (2m x 4n), BK=64, double-buffered
// 128KB LDS, 4-phase-per-K-step schedule with counted vmcnt (never 0 in the
// steady loop), setprio around MFMA clusters, pre-swizzled conflict-free
// ds_read_b128, global_load_lds width-16 staging.
__global__ __launch_bounds__(512, 2) void scoreA_kernel(
    const uint4* __restrict__ gp, const uint4* __restrict__ qp,
    float* __restrict__ bmaxT)
{
    extern __shared__ char lds[];   // 131072 B: buf0 [A0|A1|B0|B1] buf1 [...]

    // XCD-chunked mapping: each XCD owns a contiguous mt range; qt fastest.
    const int bid = blockIdx.x;
    const int xcd = bid & 7, j = bid >> 3;
    const int csz = (xcd < 7) ? 49 : 48;
    if (j >= csz * 8) return;
    const int cbase = (xcd < 7) ? xcd * 49 : 343;
    const int qt = j & 7;
    const int mt = cbase + (j >> 3);

    const int tid = threadIdx.x;
    const int wid = tid >> 6, lane = tid & 63;
    const int wr = wid >> 2, wc = wid & 3;          // 2 x 4 wave grid
    const int r16 = lane & 15, rhi = lane >> 4;
    const int sw0 = ((rhi ^ (r16 & 7)) << 4);
    const int sw1 = sw0 ^ 64;

    const uint4* gsrc = gp + (size_t)mt * 8192;
    const uint4* qsrc = qp + (size_t)qt * 8192;

    f32x4 acc[8][4];
    #pragma unroll
    for (int i = 0; i < 8; ++i)
        #pragma unroll
        for (int n = 0; n < 4; ++n) acc[i][n] = (f32x4){0.f, 0.f, 0.f, 0.f};
    bf16x8 aR[8], bR[4];

    // prologue: 6 half-tiles in canonical order, then wait the 4 for t=0
    STAGE_HALF(0,             GA(0, 0));   // A0@0
    STAGE_HALF(49152,         QB(0, 1));   // B1@0
    STAGE_HALF(16384,         GA(0, 1));   // A1@0
    STAGE_HALF(32768,         QB(0, 0));   // B0@0
    STAGE_HALF(65536,         GA(1, 0));   // A0@1
    STAGE_HALF(65536 + 49152, QB(1, 1));   // B1@1
    VMCNT(4);
    BAR;

    #pragma unroll
    for (int t = 0; t < 4; ++t) {
        const int c = (t & 1) * 65536;
        const int o = ((t + 1) & 1) * 65536;
        // P1: quadrant (m0,n0); stage A1@t+1
        READ_A(c, 0); READ_B(c, 0);
        if (t < 3) STAGE_HALF(o + 16384, GA(t + 1, 1));
        BAR; LGKM0;
        __builtin_amdgcn_s_setprio(1); MFMA16(0, 0); __builtin_amdgcn_s_setprio(0);
        BAR;
        // P2: (m0,n1); stage B0@t+1
        READ_B(c, 1);
        if (t < 3) STAGE_HALF(o + 32768, QB(t + 1, 0));
        BAR; LGKM0;
        __builtin_amdgcn_s_setprio(1); MFMA16(0, 1); __builtin_amdgcn_s_setprio(0);
        BAR;
        // P3: (m1,n1); stage A0@t+2 (region free since P1)
        READ_A(c, 1);
        if (t < 2) STAGE_HALF(c, GA(t + 2, 0));
        BAR; LGKM0;
        __builtin_amdgcn_s_setprio(1); MFMA16(1, 1); __builtin_amdgcn_s_setprio(0);
        BAR;
        // P4: (m1,n0); stage B1@t+2 (region free since P3)
        READ_B(c, 0);
        if (t < 2) STAGE_HALF(c + 49152, QB(t + 2, 1));
        BAR; LGKM0;
        __builtin_amdgcn_s_setprio(1); MFMA16(1, 0); __builtin_amdgcn_s_setprio(0);
        if (t < 2) { VMCNT(4); } else if (t == 2) { VMCNT(0); }
        BAR;
    }

    // epilogue: per-query max over each 64-row group this wave owns
    float colmax[2][4];
    #pragma unroll
    for (int mi = 0; mi < 2; ++mi)
        #pragma unroll
        for (int nj = 0; nj < 4; ++nj) colmax[mi][nj] = -FLT_MAX;
    #pragma unroll
    for (int mi = 0; mi < 2; ++mi)
        #pragma unroll
        for (int f = 0; f < 4; ++f)
            #pragma unroll
            for (int jj = 0; jj < 4; ++jj) {
                int row = mt * 256 + wr * 64 + f * 16 + mi * 128 + rhi * 4 + jj;
                bool valid = row < M_G;
                #pragma unroll
                for (int nj = 0; nj < 4; ++nj) {
                    float s = acc[mi * 4 + f][nj][jj];
                    colmax[mi][nj] = fmaxf(colmax[mi][nj], valid ? s : -FLT_MAX);
                }
            }
    #pragma unroll
    for (int mi = 0; mi < 2; ++mi)
        #pragma unroll
        for (int nj = 0; nj < 4; ++nj) {
            float v = colmax[mi][nj];
            v = fmaxf(v, __shfl_xor(v, 16));
            v = fmaxf(v, __shfl_xor(v, 32));
            if (lane < 16) {
                int qn = qt * 256 + wc * 32 + (nj & 1) * 16 + (nj >> 1) * 128 + lane;
                int group = mt * 4 + mi * 2 + wr;
                bmaxT[(size_t)qn * GSTRIDE + group] = v;
            }
        }
}

// Phase B: s1 from own bmaxT scan; exact fp32 rescore of candidate groups.
__global__ __launch_bounds__(256) void phaseB_kernel(
    const float* __restrict__ q, const float* __restrict__ g,
    const float* __restrict__ bmaxT,
    const int* __restrict__ cat, const int* __restrict__ shp,
    int* __restrict__ out)
{
    __shared__ __align__(16) float qrow[DIM];
    __shared__ int glist[NG2];
    __shared__ int ng;
    __shared__ float smax[4];
    __shared__ float rbs[4];
    __shared__ int rbi[4];

    const int qi = blockIdx.x;
    const int tid = threadIdx.x;
    const int lane = tid & 63, wid = tid >> 6;
    if (tid < 64)
        *(float4*)&qrow[tid * 4] = *(const float4*)(q + (size_t)qi * DIM + tid * 4);
    if (tid == 0) ng = 0;

    // pass 1: s1 = max over groups
    float m = -FLT_MAX;
    for (int gr = tid; gr < NG2; gr += 256)
        m = fmaxf(m, bmaxT[(size_t)qi * GSTRIDE + gr]);
    #pragma unroll
    for (int o = 32; o; o >>= 1) m = fmaxf(m, __shfl_xor(m, o));
    if (lane == 0) smax[wid] = m;
    __syncthreads();
    const float thr = fmaxf(fmaxf(smax[0], smax[1]), fmaxf(smax[2], smax[3])) - MARGIN;

    // pass 2: collect candidate groups
    for (int gr = tid; gr < NG2; gr += 256)
        if (bmaxT[(size_t)qi * GSTRIDE + gr] >= thr)
            glist[atomicAdd(&ng, 1)] = gr;
    __syncthreads();

    float bs = -FLT_MAX;
    int bi = 0x7fffffff;
    const int r = tid >> 2, p = tid & 3;
    const int n = ng;
    for (int i = 0; i < n; ++i) {
        int mm = glist[i] * 64 + r;
        if (mm < M_G) {
            const float* grow = g + (size_t)mm * DIM + p * 64;
            const float* qr = qrow + p * 64;
            float s = 0.f, ssq = 0.f;
            #pragma unroll
            for (int jj = 0; jj < 16; ++jj) {
                float4 gv = *(const float4*)(grow + jj * 4);
                float4 qv = *(const float4*)(qr + jj * 4);
                s += gv.x * qv.x + gv.y * qv.y + gv.z * qv.z + gv.w * qv.w;
                ssq += gv.x * gv.x + gv.y * gv.y + gv.z * gv.z + gv.w * gv.w;
            }
            s += __shfl_xor(s, 1);  s += __shfl_xor(s, 2);
            ssq += __shfl_xor(ssq, 1);  ssq += __shfl_xor(ssq, 2);
            s *= 1.0f / fmaxf(sqrtf(ssq), 1e-12f);
            if (p == 0 && (s > bs || (s == bs && mm < bi))) { bs = s; bi = mm; }
        }
    }
    #pragma unroll
    for (int o = 1; o < 64; o <<= 1) {
        float os = __shfl_xor(bs, o);
        int oi = __shfl_xor(bi, o);
        if (os > bs || (os == bs && oi < bi)) { bs = os; bi = oi; }
    }
    if (lane == 0) { rbs[wid] = bs; rbi[wid] = bi; }
    __syncthreads();
    if (tid == 0) {
        #pragma unroll
        for (int w = 1; w < 4; ++w)
            if (rbs[w] > bs || (rbs[w] == bs && rbi[w] < bi)) { bs = rbs[w]; bi = rbi[w]; }
        out[qi] = cat[bi];
        out[N_Q + qi] = shp[bi];
    }
}

extern "C" void kernel_launch(void* const* d_in, const int* in_sizes, int n_in,
                              void* d_out, int out_size, void* d_ws, size_t ws_size,
                              hipStream_t stream) {
    const float* q = (const float*)d_in[0];    // [2048,256] fp32
    const float* g = (const float*)d_in[1];    // [100000,256] fp32
    const int* cat = (const int*)d_in[2];      // [100000] int32
    const int* shp = (const int*)d_in[3];      // [100000] int32
    int* out = (int*)d_out;                    // [2048 cat | 2048 shape] int32

    char* ws = (char*)d_ws;
    uint4* gp    = (uint4*)(ws + WS_GP);
    uint4* qp    = (uint4*)(ws + WS_QP);
    float* bmaxT = (float*)(ws + WS_BMAX);

    static bool attr_set = false;
    hipFuncSetAttribute((const void*)scoreA_kernel,
                        hipFuncAttributeMaxDynamicSharedMemorySize, 131072);
    (void)attr_set;

    pack_kernel<<<25512, 256, 0, stream>>>(g, q, gp, qp);
    scoreA_kernel<<<3136, 512, 131072, stream>>>(gp, qp, bmaxT);
    phaseB_kernel<<<N_Q, 256, 0, stream>>>(q, g, bmaxT, cat, shp, out);
}

// Round 5
// 208.289 us; speedup vs baseline: 7.0095x; 1.1263x over previous
//
#include <hip/hip_runtime.h>
#include <hip/hip_fp16.h>
#include <math.h>
#include <float.h>

#define M_G 100000
#define M_PAD 100096         // 782 * 128
#define N_Q 2048
#define DIM 256
#define NMT 782              // 128-row gallery tiles
#define NQT 8                // 256-col query tiles
#define NG2 1564             // 64-row groups = NMT*2
#define GSTRIDE 1568         // padded group stride for bmaxT rows
#define MARGIN 0.008f        // > 2*(2^-11 RN + ~1e-3 FTZ + accum) fp16 bound

typedef _Float16 f16x8 __attribute__((ext_vector_type(8)));
typedef float f32x4 __attribute__((ext_vector_type(4)));

// ws layout (bytes)
#define WS_GP    0                   // 782 tiles * 64KB = 51,249,152
#define WS_QP    51249152            // 8 tiles * 128KB  =  1,048,576
#define WS_BMAX  52297728            // 2048*1568*4      = 12,845,056

__device__ inline unsigned pack_h2(float a, float b) {
    __half ha = __float2half(a), hb = __float2half(b);   // RN
    return (unsigned)*(unsigned short*)&ha | ((unsigned)*(unsigned short*)&hb << 16);
}
__device__ inline void gload_lds16(const void* gsrc, void* ldst) {
    __builtin_amdgcn_global_load_lds(
        (const __attribute__((address_space(1))) unsigned int*)gsrc,
        (__attribute__((address_space(3))) unsigned int*)ldst, 16, 0, 0);
}

#define BAR __builtin_amdgcn_s_barrier()
#define LGKM0 { asm volatile("s_waitcnt lgkmcnt(0)" ::: "memory"); \
                __builtin_amdgcn_sched_barrier(0); }
#define VMCNT0 { asm volatile("s_waitcnt vmcnt(0)" ::: "memory"); \
                 __builtin_amdgcn_sched_barrier(0); }

// Normalize rows, fp32->fp16 (RN), store in per-K-step swizzled LDS image
// layout. Gallery tile = 128 rows: chunk (mt*4+kt) of 1024 uint4, granule
// (rl, gg) at rl*8 + (gg ^ (rl&7)). Query tile = 256 rows: chunk (qt*4+kt)
// of 2048 uint4, same granule rule. Gallery pad rows (>=M_G) zeroed.
__global__ __launch_bounds__(256) void pack_kernel(
    const float* __restrict__ g, const float* __restrict__ q,
    uint4* __restrict__ gp, uint4* __restrict__ qp)
{
    const int b = blockIdx.x;
    const int w4 = threadIdx.x >> 6, lane = threadIdx.x & 63;
    const bool isg = b < (M_PAD / 4);
    const int row = (isg ? b : b - M_PAD / 4) * 4 + w4;
    const bool real = !isg || row < M_G;
    const float* src = isg ? g + (size_t)row * DIM : q + (size_t)row * DIM;

    float inv = 0.0f;
    if (real) {
        float4 v = ((const float4*)src)[lane];
        float ss = v.x * v.x + v.y * v.y + v.z * v.z + v.w * v.w;
        #pragma unroll
        for (int o = 32; o; o >>= 1) ss += __shfl_xor(ss, o);
        inv = 1.0f / fmaxf(sqrtf(ss), 1e-12f);
    }
    if (lane < 32) {
        uint4 w = make_uint4(0u, 0u, 0u, 0u);
        if (real) {
            float4 a = ((const float4*)src)[lane * 2];
            float4 c = ((const float4*)src)[lane * 2 + 1];
            w.x = pack_h2(a.x * inv, a.y * inv);
            w.y = pack_h2(a.z * inv, a.w * inv);
            w.z = pack_h2(c.x * inv, c.y * inv);
            w.w = pack_h2(c.z * inv, c.w * inv);
        }
        const int kt = lane >> 3, gg = lane & 7;
        if (isg) {
            int mt = row >> 7, rl = row & 127;
            gp[(size_t)(mt * 4 + kt) * 1024 + rl * 8 + (gg ^ (rl & 7))] = w;
        } else {
            int qt = row >> 8, rl = row & 255;
            qp[(size_t)(qt * 4 + kt) * 2048 + rl * 8 + (gg ^ (rl & 7))] = w;
        }
    }
}

// Phase A: fp16 MFMA GEMM. Block = 128 gallery rows x 256 queries, 4 waves
// (each 128 x 64), BK=64, single-buffered 48KB LDS, 2 blocks/CU for
// inter-block overlap of staging stalls and MFMA. Zero-conflict swizzled
// ds_read_b128; global_load_lds width-16 staging; q-fastest XCD-chunked grid.
__global__ __launch_bounds__(256, 2) void scoreA_kernel(
    const uint4* __restrict__ gp, const uint4* __restrict__ qp,
    float* __restrict__ bmaxT)
{
    __shared__ __align__(16) char lds[49152];   // As 16KB | Bs 32KB

    const int bid = blockIdx.x;
    const int xcd = bid & 7, j = bid >> 3;
    const int csz = (xcd < 6) ? 98 : 97;
    if (j >= csz * NQT) return;
    const int cbase = (xcd < 6) ? xcd * 98 : 588 + (xcd - 6) * 97;
    const int qt = j & 7;
    const int mt = cbase + (j >> 3);

    const int tid = threadIdx.x;
    const int w = tid >> 6, lane = tid & 63;
    const int r16 = lane & 15, rhi = lane >> 4;

    const uint4* ga = gp + (size_t)mt * 4096;
    const uint4* qb = qp + (size_t)qt * 8192;

    f32x4 acc[8][4];
    #pragma unroll
    for (int f = 0; f < 8; ++f)
        #pragma unroll
        for (int n = 0; n < 4; ++n) acc[f][n] = (f32x4){0.f, 0.f, 0.f, 0.f};
    f16x8 aR[8], bR[4];

    for (int kt = 0; kt < 4; ++kt) {
        // stage A (1024 uint4) + B (2048 uint4), linear
        #pragma unroll
        for (int p = 0; p < 4; ++p)
            gload_lds16(ga + (size_t)kt * 1024 + p * 256 + tid,
                        lds + (p * 256 + tid) * 16);
        #pragma unroll
        for (int p = 0; p < 8; ++p)
            gload_lds16(qb + (size_t)kt * 2048 + p * 256 + tid,
                        lds + 16384 + (p * 256 + tid) * 16);
        VMCNT0;
        BAR;
        #pragma unroll
        for (int kk = 0; kk < 2; ++kk) {
            #pragma unroll
            for (int f = 0; f < 8; ++f) {
                int row = f * 16 + r16;
                aR[f] = *(const f16x8*)(lds + row * 128 +
                                        (((kk * 4 + rhi) ^ (row & 7)) << 4));
            }
            #pragma unroll
            for (int f = 0; f < 4; ++f) {
                int row = w * 64 + f * 16 + r16;
                bR[f] = *(const f16x8*)(lds + 16384 + row * 128 +
                                        (((kk * 4 + rhi) ^ (row & 7)) << 4));
            }
            #pragma unroll
            for (int f = 0; f < 8; ++f)
                #pragma unroll
                for (int fj = 0; fj < 4; ++fj)
                    acc[f][fj] = __builtin_amdgcn_mfma_f32_16x16x32_f16(
                        aR[f], bR[fj], acc[f][fj], 0, 0, 0);
        }
        BAR;
    }

    // epilogue: per-query max over each 64-row group (frags 0-3, 4-7)
    #pragma unroll
    for (int g2 = 0; g2 < 2; ++g2) {
        float cm[4] = {-FLT_MAX, -FLT_MAX, -FLT_MAX, -FLT_MAX};
        #pragma unroll
        for (int f = 0; f < 4; ++f) {
            int fr = g2 * 4 + f;
            #pragma unroll
            for (int jj = 0; jj < 4; ++jj) {
                int row = mt * 128 + fr * 16 + rhi * 4 + jj;
                bool valid = row < M_G;
                #pragma unroll
                for (int fj = 0; fj < 4; ++fj)
                    cm[fj] = fmaxf(cm[fj], valid ? acc[fr][fj][jj] : -FLT_MAX);
            }
        }
        #pragma unroll
        for (int fj = 0; fj < 4; ++fj) {
            float v = cm[fj];
            v = fmaxf(v, __shfl_xor(v, 16));
            v = fmaxf(v, __shfl_xor(v, 32));
            if (lane < 16) {
                int qn = qt * 256 + w * 64 + fj * 16 + lane;
                bmaxT[(size_t)qn * GSTRIDE + mt * 2 + g2] = v;
            }
        }
    }
}

// Phase B: s1 scan + candidate collection + exact fp32 rescore.
__global__ __launch_bounds__(256) void phaseB_kernel(
    const float* __restrict__ q, const float* __restrict__ g,
    const float* __restrict__ bmaxT,
    const int* __restrict__ cat, const int* __restrict__ shp,
    int* __restrict__ out)
{
    __shared__ __align__(16) float qrow[DIM];
    __shared__ int glist[NG2];
    __shared__ int ng;
    __shared__ float smax[4];
    __shared__ float rbs[4];
    __shared__ int rbi[4];

    const int qi = blockIdx.x;
    const int tid = threadIdx.x;
    const int lane = tid & 63, wid = tid >> 6;
    if (tid < 64)
        *(float4*)&qrow[tid * 4] = *(const float4*)(q + (size_t)qi * DIM + tid * 4);
    if (tid == 0) ng = 0;

    float m = -FLT_MAX;
    for (int gr = tid; gr < NG2; gr += 256)
        m = fmaxf(m, bmaxT[(size_t)qi * GSTRIDE + gr]);
    #pragma unroll
    for (int o = 32; o; o >>= 1) m = fmaxf(m, __shfl_xor(m, o));
    if (lane == 0) smax[wid] = m;
    __syncthreads();
    const float thr = fmaxf(fmaxf(smax[0], smax[1]), fmaxf(smax[2], smax[3])) - MARGIN;

    for (int gr = tid; gr < NG2; gr += 256)
        if (bmaxT[(size_t)qi * GSTRIDE + gr] >= thr)
            glist[atomicAdd(&ng, 1)] = gr;
    __syncthreads();

    float bs = -FLT_MAX;
    int bi = 0x7fffffff;
    const int r = tid >> 2, p = tid & 3;
    const int n = ng;
    for (int i = 0; i < n; ++i) {
        int mm = glist[i] * 64 + r;
        if (mm < M_G) {
            const float* grow = g + (size_t)mm * DIM + p * 64;
            const float* qr = qrow + p * 64;
            float s = 0.f, ssq = 0.f;
            #pragma unroll
            for (int jj = 0; jj < 16; ++jj) {
                float4 gv = *(const float4*)(grow + jj * 4);
                float4 qv = *(const float4*)(qr + jj * 4);
                s += gv.x * qv.x + gv.y * qv.y + gv.z * qv.z + gv.w * qv.w;
                ssq += gv.x * gv.x + gv.y * gv.y + gv.z * gv.z + gv.w * gv.w;
            }
            s += __shfl_xor(s, 1);  s += __shfl_xor(s, 2);
            ssq += __shfl_xor(ssq, 1);  ssq += __shfl_xor(ssq, 2);
            s *= 1.0f / fmaxf(sqrtf(ssq), 1e-12f);
            if (p == 0 && (s > bs || (s == bs && mm < bi))) { bs = s; bi = mm; }
        }
    }
    #pragma unroll
    for (int o = 1; o < 64; o <<= 1) {
        float os = __shfl_xor(bs, o);
        int oi = __shfl_xor(bi, o);
        if (os > bs || (os == bs && oi < bi)) { bs = os; bi = oi; }
    }
    if (lane == 0) { rbs[wid] = bs; rbi[wid] = bi; }
    __syncthreads();
    if (tid == 0) {
        #pragma unroll
        for (int ww = 1; ww < 4; ++ww)
            if (rbs[ww] > bs || (rbs[ww] == bs && rbi[ww] < bi)) { bs = rbs[ww]; bi = rbi[ww]; }
        out[qi] = cat[bi];
        out[N_Q + qi] = shp[bi];
    }
}

extern "C" void kernel_launch(void* const* d_in, const int* in_sizes, int n_in,
                              void* d_out, int out_size, void* d_ws, size_t ws_size,
                              hipStream_t stream) {
    const float* q = (const float*)d_in[0];    // [2048,256] fp32
    const float* g = (const float*)d_in[1];    // [100000,256] fp32
    const int* cat = (const int*)d_in[2];      // [100000] int32
    const int* shp = (const int*)d_in[3];      // [100000] int32
    int* out = (int*)d_out;                    // [2048 cat | 2048 shape] int32

    char* ws = (char*)d_ws;
    uint4* gp    = (uint4*)(ws + WS_GP);
    uint4* qp    = (uint4*)(ws + WS_QP);
    float* bmaxT = (float*)(ws + WS_BMAX);

    pack_kernel<<<M_PAD / 4 + N_Q / 4, 256, 0, stream>>>(g, q, gp, qp);
    scoreA_kernel<<<8 * 98 * NQT, 256, 0, stream>>>(gp, qp, bmaxT);
    phaseB_kernel<<<N_Q, 256, 0, stream>>>(q, g, bmaxT, cat, shp, out);
}